// Round 9
// baseline (345.045 us; speedup 1.0000x reference)
//
#include <hip/hip_runtime.h>
#include <stdint.h>

#define NROWS 32768
#define DIMS  256
#define KCB   1024
#define BM 128
#define BN 128
#define GY (KCB/BN)   // 8 code-blocks
#define MARGIN 0.35f

typedef _Float16 half8   __attribute__((ext_vector_type(8)));
typedef float    f32x4   __attribute__((ext_vector_type(4)));
typedef short    short4v __attribute__((ext_vector_type(4)));
typedef short    short8v __attribute__((ext_vector_type(8)));

// async global->LDS, 16B per lane; LDS dest = wave-uniform base + lane*16
__device__ __forceinline__ void gload_lds16(const void* g, void* l) {
    __builtin_amdgcn_global_load_lds(
        (const __attribute__((address_space(1))) uint32_t*)g,
        (__attribute__((address_space(3))) uint32_t*)l, 16, 0, 0);
}

__device__ __forceinline__ short f16h(float v) {
    _Float16 hh = (_Float16)v;
    return __builtin_bit_cast(short, hh);
}

// ---- X -> fragment-ordered f16 (h-plane only) ----------------------------
// frag(G=row-group of 16, c=k-chunk of 32) is 1KB: lane l holds row
// G*16+(l&15), k = c*32+(l>>4)*8..+7; byte addr = G*8192 + c*1024 + l*16
__global__ __launch_bounds__(256) void xsplit(const float* __restrict__ x,
                                              short* __restrict__ Xh) {
    int T = blockIdx.x * 256 + threadIdx.x;
    int l = T & 63, c = (T >> 6) & 7, G = T >> 9;
    int row = G * 16 + (l & 15);
    int kb  = c * 32 + (l >> 4) * 8;
    const f32x4* src = (const f32x4*)(x + (size_t)row * DIMS + kb);
    f32x4 a = src[0], b = src[1];
    short8v h;
    #pragma unroll
    for (int e = 0; e < 4; ++e) { h[e] = f16h(a[e]); h[4 + e] = f16h(b[e]); }
    *(short8v*)(Xh + (size_t)G * 4096 + c * 512 + l * 8) = h;
}

// ---- E -> fragment-ordered f16 (h-plane) + he2 ---------------------------
__global__ __launch_bounds__(256) void esplit(const float* __restrict__ embed,
                                              short* __restrict__ Eh,
                                              float* __restrict__ he2) {
    int r = blockIdx.x * 4 + (threadIdx.x >> 6);   // code row 0..1023
    int l = threadIdx.x & 63;
    f32x4 v = ((const f32x4*)(embed + (size_t)r * DIMS))[l];
    float s = v[0]*v[0] + v[1]*v[1] + v[2]*v[2] + v[3]*v[3];
    #pragma unroll
    for (int off = 32; off > 0; off >>= 1) s += __shfl_down(s, off, 64);
    if (l == 0) he2[r] = 0.5f * s;
    int G = r >> 4, cc = l >> 3;
    int fl = (r & 15) + 16 * ((l >> 1) & 3);
    size_t base = (size_t)G * 4096 + cc * 512 + fl * 8 + (l & 1) * 4;
    short4v h;
    #pragma unroll
    for (int e = 0; e < 4; ++e) h[e] = f16h(v[e]);
    *(short4v*)(Eh + base) = h;
}

// ---- approx GEMM + argmax(best,2nd): single-plane, 16KB tile -------------
__global__ __launch_bounds__(256, 3) void vq_mfma(
    const short* __restrict__ Xh, const short* __restrict__ Eh,
    const float* __restrict__ he2, float4* __restrict__ part)
{
    __shared__ char  lds[16384];
    __shared__ float sarr[BM * 2];
    __shared__ int   iarr[BM * 2];
    __shared__ float barr[BM * 2];

    const int t = threadIdx.x, lane = t & 63, w = t >> 6;
    const int wm = w >> 1, wn = w & 1;
    const int sid = blockIdx.x;
    const int xcd = sid & 7, j = sid >> 3;
    const int rb = xcd * 32 + (j >> 3), cb = j & 7;
    const int rowBase = rb * BM, colBase = cb * BN;

    // wave w stages frags f=4w..4w+3 (f<8: A row-group f; else B group f-8)
    const char* gsrc[4];
    int ldso[4];
    #pragma unroll
    for (int p = 0; p < 4; ++p) {
        int f = w * 4 + p;
        ldso[p] = f * 1024;
        const char* b = (f < 8)
            ? (const char*)Xh + (size_t)(rb * 8 + f) * 8192
            : (const char*)Eh + (size_t)(cb * 8 + (f - 8)) * 8192;
        gsrc[p] = b + lane * 16;
    }
    const char* A0 = lds +        (wm * 4) * 1024 + lane * 16;
    const char* B0 = lds + 8192 + (wn * 4) * 1024 + lane * 16;

    f32x4 acc[4][4];
    #pragma unroll
    for (int m = 0; m < 4; ++m)
        #pragma unroll
        for (int n = 0; n < 4; ++n) acc[m][n] = (f32x4){0.f, 0.f, 0.f, 0.f};

    #pragma unroll
    for (int p = 0; p < 4; ++p) gload_lds16(gsrc[p], lds + ldso[p]);

    #pragma unroll
    for (int c = 0; c < 8; ++c) {
        asm volatile("s_waitcnt vmcnt(0)" ::: "memory");
        __builtin_amdgcn_sched_barrier(0);
        __builtin_amdgcn_s_barrier();                  // tile c resident

        half8 Ah[4], Bh[4];
        #pragma unroll
        for (int m = 0; m < 4; ++m) Ah[m] = *(const half8*)(A0 + m * 1024);
        #pragma unroll
        for (int n = 0; n < 4; ++n) Bh[n] = *(const half8*)(B0 + n * 1024);
        asm volatile("s_waitcnt lgkmcnt(0)" ::: "memory");
        __builtin_amdgcn_sched_barrier(0);
        __builtin_amdgcn_s_barrier();                  // all waves done reading

        if (c < 7) {
            #pragma unroll
            for (int p = 0; p < 4; ++p)
                gload_lds16(gsrc[p] + (c + 1) * 1024, lds + ldso[p]);
        }
        __builtin_amdgcn_sched_barrier(0);

        __builtin_amdgcn_s_setprio(1);
        #pragma unroll
        for (int m = 0; m < 4; ++m)
            #pragma unroll
            for (int n = 0; n < 4; ++n)
                acc[m][n] = __builtin_amdgcn_mfma_f32_16x16x32_f16(Ah[m], Bh[n], acc[m][n], 0, 0, 0);
        __builtin_amdgcn_s_setprio(0);
    }

    // epilogue: per-row best + second-best (first-index tie-break)
    float h2[4];
    const int c15 = lane & 15;
    #pragma unroll
    for (int n = 0; n < 4; ++n) h2[n] = he2[colBase + 64 * wn + 16 * n + c15];
    const int colg0 = colBase + 64 * wn + c15;

    #pragma unroll
    for (int m = 0; m < 4; ++m) {
        #pragma unroll
        for (int reg = 0; reg < 4; ++reg) {
            float b1 = acc[m][0][reg] - h2[0];
            int   i1 = colg0;
            float b2 = -3.4e38f;
            #pragma unroll
            for (int n = 1; n < 4; ++n) {
                float s = acc[m][n][reg] - h2[n];
                if (s > b1) { b2 = b1; b1 = s; i1 = colg0 + 16 * n; }
                else        { b2 = fmaxf(b2, s); }
            }
            #pragma unroll
            for (int msk = 1; msk <= 8; msk <<= 1) {
                float ob1 = __shfl_xor(b1, msk, 64);
                int   oi1 = __shfl_xor(i1, msk, 64);
                float ob2 = __shfl_xor(b2, msk, 64);
                if (ob1 > b1 || (ob1 == b1 && oi1 < i1)) {
                    b2 = fmaxf(b1, ob2); b1 = ob1; i1 = oi1;
                } else {
                    b2 = fmaxf(b2, ob1);
                }
            }
            if (c15 == 0) {
                int row = 64 * wm + 16 * m + 4 * (lane >> 4) + reg;
                sarr[row * 2 + wn] = b1;
                iarr[row * 2 + wn] = i1;
                barr[row * 2 + wn] = b2;
            }
        }
    }
    __syncthreads();
    if (t < BM) {
        float s0 = sarr[t*2], s1 = sarr[t*2+1];
        int   i0 = iarr[t*2], i1 = iarr[t*2+1];
        float c0 = barr[t*2], c1 = barr[t*2+1];
        float b1, b2; int bi;
        if (s1 > s0) { b1 = s1; bi = i1; b2 = fmaxf(s0, c1); }   // i0<i1: ties keep i0
        else         { b1 = s0; bi = i0; b2 = fmaxf(s1, c0); }
        part[(size_t)(rowBase + t) * GY + cb] =
            make_float4(b1, __int_as_float(bi), b2, 0.f);
    }
}

// ---- combine 8 partials, write approx result, flag near-ties -------------
__global__ __launch_bounds__(256) void vq_combine(
    const float4* __restrict__ part, const float* __restrict__ embed,
    float* __restrict__ outq, float* __restrict__ outi,
    int* __restrict__ flagCount, int* __restrict__ flagList)
{
    __shared__ int idxS[256];
    const int t = threadIdx.x;
    const int rowBase = blockIdx.x * 256;
    const int row = rowBase + t;

    float4 p = part[(size_t)row * GY];
    float b1 = p.x; int i1 = __float_as_int(p.y); float b2 = p.z;
    #pragma unroll
    for (int g = 1; g < GY; ++g) {
        float4 q = part[(size_t)row * GY + g];
        float c1 = q.x; int j1 = __float_as_int(q.y); float c2 = q.z;
        if (c1 > b1 || (c1 == b1 && j1 < i1)) { b2 = fmaxf(b1, c2); b1 = c1; i1 = j1; }
        else                                  { b2 = fmaxf(b2, c1); }
    }
    idxS[t] = i1;
    outi[row] = (float)i1;
    if (b1 - b2 < MARGIN) {
        int s = atomicAdd(flagCount, 1);
        if (s < NROWS) flagList[s] = row;
    }
    __syncthreads();

    #pragma unroll 4
    for (int q = 0; q < 64; ++q) {
        int f = t + 256 * q;
        int r = f >> 6, c4 = f & 63;
        int e = idxS[r];
        f32x4 v = *(const f32x4*)(embed + (size_t)e * DIMS + c4 * 4);
        *(f32x4*)(outq + (size_t)(rowBase + r) * DIMS + c4 * 4) = v;
    }
}

// ---- exact rescue: f32 fmaf chain bitwise == round-2 verified kernel -----
__global__ __launch_bounds__(256) void vq_rescue(
    const float* __restrict__ x, const float* __restrict__ embed,
    const float* __restrict__ he2,
    const int* __restrict__ flagCount, const int* __restrict__ flagList,
    float* __restrict__ outq, float* __restrict__ outi)
{
    __shared__ float xs[DIMS];
    __shared__ float sred[256];
    __shared__ int   ired[256];
    const int t = threadIdx.x;
    int n = *flagCount; if (n > NROWS) n = NROWS;

    for (int it = blockIdx.x; it < n; it += gridDim.x) {
        int row = flagList[it];
        __syncthreads();
        xs[t] = x[(size_t)row * DIMS + t];
        __syncthreads();

        float best = -3.4e38f; int bi = 0;
        #pragma unroll
        for (int cc = 0; cc < 4; ++cc) {
            int code = t + cc * 256;
            const f32x4* er = (const f32x4*)(embed + (size_t)code * DIMS);
            float acc = 0.f;
            #pragma unroll 8
            for (int k4 = 0; k4 < 64; ++k4) {
                f32x4 e4 = er[k4];
                f32x4 x4 = *(const f32x4*)(xs + k4 * 4);
                acc = fmaf(x4[0], e4[0], acc);
                acc = fmaf(x4[1], e4[1], acc);
                acc = fmaf(x4[2], e4[2], acc);
                acc = fmaf(x4[3], e4[3], acc);
            }
            float s = acc - he2[code];
            if (s > best) { best = s; bi = code; }     // ascending codes
        }
        sred[t] = best; ired[t] = bi;
        __syncthreads();
        for (int off = 128; off; off >>= 1) {
            if (t < off) {
                float s2 = sred[t + off]; int i2 = ired[t + off];
                if (s2 > sred[t] || (s2 == sred[t] && i2 < ired[t])) {
                    sred[t] = s2; ired[t] = i2;
                }
            }
            __syncthreads();
        }
        int win = ired[0];
        if (t == 0) outi[row] = (float)win;
        outq[(size_t)row * DIMS + t] = embed[(size_t)win * DIMS + t];
    }
}

extern "C" void kernel_launch(void* const* d_in, const int* in_sizes, int n_in,
                              void* d_out, int out_size, void* d_ws, size_t ws_size,
                              hipStream_t stream) {
    const float* x     = (const float*)d_in[0];
    const float* embed = (const float*)d_in[1];
    char* ws = (char*)d_ws;
    float*  he2      = (float*)ws;                          // 4 KB
    int*    flagCnt  = (int*)(ws + 4096);                   // 4 B
    float4* part     = (float4*)(ws + 8192);                // 4 MB
    short*  Xh       = (short*)(ws + 8192 + 4194304);       // 16.8 MB
    short*  Eh       = (short*)(ws + 8192 + 4194304 + 16777216);  // 512 KB
    int*    flagList = (int*)(ws + 8192 + 4194304 + 16777216 + 524288); // 128 KB
    float*  out  = (float*)d_out;
    float*  outi = out + (size_t)NROWS * DIMS;

    hipMemsetAsync(flagCnt, 0, 4, stream);
    xsplit<<<4096, 256, 0, stream>>>(x, Xh);
    esplit<<<KCB / 4, 256, 0, stream>>>(embed, Eh, he2);
    vq_mfma<<<(NROWS / BM) * GY, 256, 0, stream>>>(Xh, Eh, he2, part);
    vq_combine<<<NROWS / 256, 256, 0, stream>>>(part, embed, out, outi, flagCnt, flagList);
    vq_rescue<<<512, 256, 0, stream>>>(x, embed, he2, flagCnt, flagList, out, outi);
}

// Round 10
// 212.676 us; speedup vs baseline: 1.6224x; 1.6224x over previous
//
#include <hip/hip_runtime.h>
#include <stdint.h>

#define NROWS 32768
#define DIMS  256
#define KCB   1024
#define BM 128
#define BN 128
#define GY (KCB/BN)   // 8 code-blocks
#define MARGIN 0.25f  // flag threshold AND rescue candidate window

typedef _Float16 half8   __attribute__((ext_vector_type(8)));
typedef float    f32x4   __attribute__((ext_vector_type(4)));
typedef short    short4v __attribute__((ext_vector_type(4)));
typedef short    short8v __attribute__((ext_vector_type(8)));

// async global->LDS, 16B per lane; LDS dest = wave-uniform base + lane*16
__device__ __forceinline__ void gload_lds16(const void* g, void* l) {
    __builtin_amdgcn_global_load_lds(
        (const __attribute__((address_space(1))) uint32_t*)g,
        (__attribute__((address_space(3))) uint32_t*)l, 16, 0, 0);
}

__device__ __forceinline__ short f16h(float v) {
    _Float16 hh = (_Float16)v;
    return __builtin_bit_cast(short, hh);
}

// ---- X -> fragment-ordered f16 (h-plane only) ----------------------------
// frag(G=row-group of 16, c=k-chunk of 32) is 1KB: lane l holds row
// G*16+(l&15), k = c*32+(l>>4)*8..+7; byte addr = G*8192 + c*1024 + l*16
__global__ __launch_bounds__(256) void xsplit(const float* __restrict__ x,
                                              short* __restrict__ Xh) {
    int T = blockIdx.x * 256 + threadIdx.x;
    int l = T & 63, c = (T >> 6) & 7, G = T >> 9;
    int row = G * 16 + (l & 15);
    int kb  = c * 32 + (l >> 4) * 8;
    const f32x4* src = (const f32x4*)(x + (size_t)row * DIMS + kb);
    f32x4 a = src[0], b = src[1];
    short8v h;
    #pragma unroll
    for (int e = 0; e < 4; ++e) { h[e] = f16h(a[e]); h[4 + e] = f16h(b[e]); }
    *(short8v*)(Xh + (size_t)G * 4096 + c * 512 + l * 8) = h;
}

// ---- E -> fragment-ordered f16 (h-plane) + he2 ---------------------------
__global__ __launch_bounds__(256) void esplit(const float* __restrict__ embed,
                                              short* __restrict__ Eh,
                                              float* __restrict__ he2) {
    int r = blockIdx.x * 4 + (threadIdx.x >> 6);   // code row 0..1023
    int l = threadIdx.x & 63;
    f32x4 v = ((const f32x4*)(embed + (size_t)r * DIMS))[l];
    float s = v[0]*v[0] + v[1]*v[1] + v[2]*v[2] + v[3]*v[3];
    #pragma unroll
    for (int off = 32; off > 0; off >>= 1) s += __shfl_down(s, off, 64);
    if (l == 0) he2[r] = 0.5f * s;
    int G = r >> 4, cc = l >> 3;
    int fl = (r & 15) + 16 * ((l >> 1) & 3);
    size_t base = (size_t)G * 4096 + cc * 512 + fl * 8 + (l & 1) * 4;
    short4v h;
    #pragma unroll
    for (int e = 0; e < 4; ++e) h[e] = f16h(v[e]);
    *(short4v*)(Eh + base) = h;
}

// ---- approx GEMM + argmax(best,2nd): BK=64, 4 stages, 32KB tile ----------
__global__ __launch_bounds__(256, 3) void vq_mfma(
    const short* __restrict__ Xh, const short* __restrict__ Eh,
    const float* __restrict__ he2, float4* __restrict__ part)
{
    __shared__ char  lds[32768];
    __shared__ float sarr[BM * 2];
    __shared__ int   iarr[BM * 2];
    __shared__ float barr[BM * 2];

    const int t = threadIdx.x, lane = t & 63, w = t >> 6;
    const int wm = w >> 1, wn = w & 1;
    const int sid = blockIdx.x;
    const int xcd = sid & 7, j = sid >> 3;
    const int rb = xcd * 32 + (j >> 3), cb = j & 7;
    const int rowBase = rb * BM, colBase = cb * BN;

    // staging: wave w stages frag-groups f=4w..4w+3, 2KB each per stage
    const char* gsrc[4];
    int ldso[4];
    #pragma unroll
    for (int p = 0; p < 4; ++p) {
        int f = w * 4 + p;
        ldso[p] = f * 2048;
        const char* b = (f < 8)
            ? (const char*)Xh + (size_t)(rb * 8 + f) * 8192
            : (const char*)Eh + (size_t)(cb * 8 + (f - 8)) * 8192;
        gsrc[p] = b + lane * 16;
    }

    f32x4 acc[4][4];
    #pragma unroll
    for (int m = 0; m < 4; ++m)
        #pragma unroll
        for (int n = 0; n < 4; ++n) acc[m][n] = (f32x4){0.f, 0.f, 0.f, 0.f};

    // prologue: stage k-chunks 0,1
    #pragma unroll
    for (int p = 0; p < 4; ++p) {
        gload_lds16(gsrc[p],        lds + ldso[p]);
        gload_lds16(gsrc[p] + 1024, lds + ldso[p] + 1024);
    }

    #pragma unroll
    for (int c = 0; c < 4; ++c) {
        asm volatile("s_waitcnt vmcnt(0)" ::: "memory");
        __builtin_amdgcn_sched_barrier(0);
        __builtin_amdgcn_s_barrier();                  // stage c resident

        half8 A0[4], B0[4];
        #pragma unroll
        for (int m = 0; m < 4; ++m)
            A0[m] = *(const half8*)(lds + ((wm * 4 + m) * 2) * 1024 + lane * 16);
        #pragma unroll
        for (int n = 0; n < 4; ++n)
            B0[n] = *(const half8*)(lds + 16384 + ((wn * 4 + n) * 2) * 1024 + lane * 16);
        asm volatile("s_waitcnt lgkmcnt(0)" ::: "memory");
        __builtin_amdgcn_sched_barrier(0);
        __builtin_amdgcn_s_setprio(1);
        #pragma unroll
        for (int m = 0; m < 4; ++m)
            #pragma unroll
            for (int n = 0; n < 4; ++n)
                acc[m][n] = __builtin_amdgcn_mfma_f32_16x16x32_f16(A0[m], B0[n], acc[m][n], 0, 0, 0);
        __builtin_amdgcn_s_setprio(0);

        half8 A1[4], B1[4];
        #pragma unroll
        for (int m = 0; m < 4; ++m)
            A1[m] = *(const half8*)(lds + ((wm * 4 + m) * 2 + 1) * 1024 + lane * 16);
        #pragma unroll
        for (int n = 0; n < 4; ++n)
            B1[n] = *(const half8*)(lds + 16384 + ((wn * 4 + n) * 2 + 1) * 1024 + lane * 16);
        asm volatile("s_waitcnt lgkmcnt(0)" ::: "memory");
        __builtin_amdgcn_sched_barrier(0);
        __builtin_amdgcn_s_barrier();                  // all reads done

        if (c < 3) {                                   // stage c+1 in place
            #pragma unroll
            for (int p = 0; p < 4; ++p) {
                gload_lds16(gsrc[p] + (c + 1) * 2048,        lds + ldso[p]);
                gload_lds16(gsrc[p] + (c + 1) * 2048 + 1024, lds + ldso[p] + 1024);
            }
        }
        __builtin_amdgcn_sched_barrier(0);

        __builtin_amdgcn_s_setprio(1);
        #pragma unroll
        for (int m = 0; m < 4; ++m)
            #pragma unroll
            for (int n = 0; n < 4; ++n)
                acc[m][n] = __builtin_amdgcn_mfma_f32_16x16x32_f16(A1[m], B1[n], acc[m][n], 0, 0, 0);
        __builtin_amdgcn_s_setprio(0);
    }

    // epilogue: per-row best + second-best (verified round 9)
    float h2[4];
    const int c15 = lane & 15;
    #pragma unroll
    for (int n = 0; n < 4; ++n) h2[n] = he2[colBase + 64 * wn + 16 * n + c15];
    const int colg0 = colBase + 64 * wn + c15;

    #pragma unroll
    for (int m = 0; m < 4; ++m) {
        #pragma unroll
        for (int reg = 0; reg < 4; ++reg) {
            float b1 = acc[m][0][reg] - h2[0];
            int   i1 = colg0;
            float b2 = -3.4e38f;
            #pragma unroll
            for (int n = 1; n < 4; ++n) {
                float s = acc[m][n][reg] - h2[n];
                if (s > b1) { b2 = b1; b1 = s; i1 = colg0 + 16 * n; }
                else        { b2 = fmaxf(b2, s); }
            }
            #pragma unroll
            for (int msk = 1; msk <= 8; msk <<= 1) {
                float ob1 = __shfl_xor(b1, msk, 64);
                int   oi1 = __shfl_xor(i1, msk, 64);
                float ob2 = __shfl_xor(b2, msk, 64);
                if (ob1 > b1 || (ob1 == b1 && oi1 < i1)) {
                    b2 = fmaxf(b1, ob2); b1 = ob1; i1 = oi1;
                } else {
                    b2 = fmaxf(b2, ob1);
                }
            }
            if (c15 == 0) {
                int row = 64 * wm + 16 * m + 4 * (lane >> 4) + reg;
                sarr[row * 2 + wn] = b1;
                iarr[row * 2 + wn] = i1;
                barr[row * 2 + wn] = b2;
            }
        }
    }
    __syncthreads();
    if (t < BM) {
        float s0 = sarr[t*2], s1 = sarr[t*2+1];
        int   i0 = iarr[t*2], i1 = iarr[t*2+1];
        float c0 = barr[t*2], c1 = barr[t*2+1];
        float b1, b2; int bi;
        if (s1 > s0) { b1 = s1; bi = i1; b2 = fmaxf(s0, c1); }   // i0<i1: ties keep i0
        else         { b1 = s0; bi = i0; b2 = fmaxf(s1, c0); }
        part[(size_t)(rowBase + t) * GY + cb] =
            make_float4(b1, __int_as_float(bi), b2, 0.f);
    }
}

// ---- combine 8 partials, write approx result, flag near-ties -------------
__global__ __launch_bounds__(256) void vq_combine(
    const float4* __restrict__ part, const float* __restrict__ embed,
    float* __restrict__ outq, float* __restrict__ outi,
    int* __restrict__ flagCount, int* __restrict__ flagList)
{
    __shared__ int idxS[256];
    const int t = threadIdx.x;
    const int rowBase = blockIdx.x * 256;
    const int row = rowBase + t;

    float4 p = part[(size_t)row * GY];
    float b1 = p.x; int i1 = __float_as_int(p.y); float b2 = p.z;
    #pragma unroll
    for (int g = 1; g < GY; ++g) {
        float4 q = part[(size_t)row * GY + g];
        float c1 = q.x; int j1 = __float_as_int(q.y); float c2 = q.z;
        if (c1 > b1 || (c1 == b1 && j1 < i1)) { b2 = fmaxf(b1, c2); b1 = c1; i1 = j1; }
        else                                  { b2 = fmaxf(b2, c1); }
    }
    idxS[t] = i1;
    outi[row] = (float)i1;
    if (b1 - b2 < MARGIN) {
        int s = atomicAdd(flagCount, 1);
        if (s < NROWS) flagList[s] = row;
    }
    __syncthreads();

    #pragma unroll 4
    for (int q = 0; q < 64; ++q) {
        int f = t + 256 * q;
        int r = f >> 6, c4 = f & 63;
        int e = idxS[r];
        f32x4 v = *(const f32x4*)(embed + (size_t)e * DIMS + c4 * 4);
        *(f32x4*)(outq + (size_t)(rowBase + r) * DIMS + c4 * 4) = v;
    }
}

// ---- exact rescue v2: candidate-based, wave-cooperative coalesced dots ---
__global__ __launch_bounds__(256) void vq_rescue(
    const float* __restrict__ x, const float* __restrict__ embed,
    const float* __restrict__ he2, const float4* __restrict__ part,
    const int* __restrict__ flagCount, const int* __restrict__ flagList,
    float* __restrict__ outq, float* __restrict__ outi)
{
    __shared__ float  xs[DIMS];
    __shared__ float4 pc[GY];
    __shared__ float  bestS[4];
    __shared__ int    bestI[4];
    const int t = threadIdx.x, lane = t & 63, w = t >> 6;
    int n = *flagCount; if (n > NROWS) n = NROWS;

    for (int it = blockIdx.x; it < n; it += gridDim.x) {
        int row = flagList[it];
        xs[t] = x[(size_t)row * DIMS + t];
        if (t < GY) pc[t] = part[(size_t)row * GY + t];
        __syncthreads();

        float B1 = pc[0].x;
        #pragma unroll
        for (int g = 1; g < GY; ++g) B1 = fmaxf(B1, pc[g].x);
        const float T = B1 - MARGIN;

        const f32x4 x4 = *(const f32x4*)(xs + lane * 4);   // loop-invariant
        float wb = -3.4e38f; int wi = 0x7fffffff;

        #pragma unroll
        for (int gg = 0; gg < 2; ++gg) {                   // wave w: blocks w, w+4
            int g = w + gg * 4;
            float4 p = pc[g];
            float b1 = p.x, b2 = p.z;
            int   i1 = __float_as_int(p.y);
            if (b2 >= T) {                                 // rare: full block
                for (int q = 0; q < BN; ++q) {
                    int code = g * BN + q;
                    f32x4 e4 = ((const f32x4*)(embed + (size_t)code * DIMS))[lane];
                    float s = fmaf(x4[3], e4[3], fmaf(x4[2], e4[2],
                              fmaf(x4[1], e4[1], x4[0] * e4[0])));
                    #pragma unroll
                    for (int msk = 1; msk <= 32; msk <<= 1) s += __shfl_xor(s, msk, 64);
                    s -= he2[code];
                    if (s > wb || (s == wb && code < wi)) { wb = s; wi = code; }
                }
            } else if (b1 >= T) {                          // common: 1 candidate
                int code = i1;
                f32x4 e4 = ((const f32x4*)(embed + (size_t)code * DIMS))[lane];
                float s = fmaf(x4[3], e4[3], fmaf(x4[2], e4[2],
                          fmaf(x4[1], e4[1], x4[0] * e4[0])));
                #pragma unroll
                for (int msk = 1; msk <= 32; msk <<= 1) s += __shfl_xor(s, msk, 64);
                s -= he2[code];
                if (s > wb || (s == wb && code < wi)) { wb = s; wi = code; }
            }
        }
        if (lane == 0) { bestS[w] = wb; bestI[w] = wi; }
        __syncthreads();

        float fb = bestS[0]; int fi = bestI[0];
        #pragma unroll
        for (int ww = 1; ww < 4; ++ww) {
            float s = bestS[ww]; int i = bestI[ww];
            if (s > fb || (s == fb && i < fi)) { fb = s; fi = i; }
        }
        if (t == 0) outi[row] = (float)fi;
        outq[(size_t)row * DIMS + t] = embed[(size_t)fi * DIMS + t];
        __syncthreads();                                   // guard xs/pc reuse
    }
}

extern "C" void kernel_launch(void* const* d_in, const int* in_sizes, int n_in,
                              void* d_out, int out_size, void* d_ws, size_t ws_size,
                              hipStream_t stream) {
    const float* x     = (const float*)d_in[0];
    const float* embed = (const float*)d_in[1];
    char* ws = (char*)d_ws;
    float*  he2      = (float*)ws;                          // 4 KB
    int*    flagCnt  = (int*)(ws + 4096);                   // 4 B
    float4* part     = (float4*)(ws + 8192);                // 4 MB
    short*  Xh       = (short*)(ws + 8192 + 4194304);       // 16.8 MB
    short*  Eh       = (short*)(ws + 8192 + 4194304 + 16777216);  // 512 KB
    int*    flagList = (int*)(ws + 8192 + 4194304 + 16777216 + 524288); // 128 KB
    float*  out  = (float*)d_out;
    float*  outi = out + (size_t)NROWS * DIMS;

    hipMemsetAsync(flagCnt, 0, 4, stream);
    xsplit<<<4096, 256, 0, stream>>>(x, Xh);
    esplit<<<KCB / 4, 256, 0, stream>>>(embed, Eh, he2);
    vq_mfma<<<(NROWS / BM) * GY, 256, 0, stream>>>(Xh, Eh, he2, part);
    vq_combine<<<NROWS / 256, 256, 0, stream>>>(part, embed, out, outi, flagCnt, flagList);
    vq_rescue<<<512, 256, 0, stream>>>(x, embed, he2, part, flagCnt, flagList, out, outi);
}

// Round 11
// 103.643 us; speedup vs baseline: 3.3292x; 2.0520x over previous
//
#include <hip/hip_runtime.h>
#include <stdint.h>

#define NROWS 32768
#define DIMS  256
#define KCB   1024
#define BM 128
#define BN 128
#define GY (KCB/BN)   // 8 code-blocks
#define MARGIN 0.25f  // flag threshold AND rescue candidate window

typedef _Float16 half8   __attribute__((ext_vector_type(8)));
typedef float    f32x4   __attribute__((ext_vector_type(4)));
typedef short    short4v __attribute__((ext_vector_type(4)));
typedef short    short8v __attribute__((ext_vector_type(8)));

// async global->LDS, 16B per lane; LDS dest = wave-uniform base + lane*16
__device__ __forceinline__ void gload_lds16(const void* g, void* l) {
    __builtin_amdgcn_global_load_lds(
        (const __attribute__((address_space(1))) uint32_t*)g,
        (__attribute__((address_space(3))) uint32_t*)l, 16, 0, 0);
}

__device__ __forceinline__ short f16h(float v) {
    _Float16 hh = (_Float16)v;
    return __builtin_bit_cast(short, hh);
}

// ---- X -> fragment-ordered f16 (h-plane only) ----------------------------
__global__ __launch_bounds__(256) void xsplit(const float* __restrict__ x,
                                              short* __restrict__ Xh) {
    int T = blockIdx.x * 256 + threadIdx.x;
    int l = T & 63, c = (T >> 6) & 7, G = T >> 9;
    int row = G * 16 + (l & 15);
    int kb  = c * 32 + (l >> 4) * 8;
    const f32x4* src = (const f32x4*)(x + (size_t)row * DIMS + kb);
    f32x4 a = src[0], b = src[1];
    short8v h;
    #pragma unroll
    for (int e = 0; e < 4; ++e) { h[e] = f16h(a[e]); h[4 + e] = f16h(b[e]); }
    *(short8v*)(Xh + (size_t)G * 4096 + c * 512 + l * 8) = h;
}

// ---- E -> fragment-ordered f16 (h-plane) + he2 ---------------------------
__global__ __launch_bounds__(256) void esplit(const float* __restrict__ embed,
                                              short* __restrict__ Eh,
                                              float* __restrict__ he2) {
    int r = blockIdx.x * 4 + (threadIdx.x >> 6);   // code row 0..1023
    int l = threadIdx.x & 63;
    f32x4 v = ((const f32x4*)(embed + (size_t)r * DIMS))[l];
    float s = v[0]*v[0] + v[1]*v[1] + v[2]*v[2] + v[3]*v[3];
    #pragma unroll
    for (int off = 32; off > 0; off >>= 1) s += __shfl_down(s, off, 64);
    if (l == 0) he2[r] = 0.5f * s;
    int G = r >> 4, cc = l >> 3;
    int fl = (r & 15) + 16 * ((l >> 1) & 3);
    size_t base = (size_t)G * 4096 + cc * 512 + fl * 8 + (l & 1) * 4;
    short4v h;
    #pragma unroll
    for (int e = 0; e < 4; ++e) h[e] = f16h(v[e]);
    *(short4v*)(Eh + base) = h;
}

// ---- approx GEMM + argmax(best,2nd): BK=64, 4 stages, 32KB tile ----------
__global__ __launch_bounds__(256, 3) void vq_mfma(
    const short* __restrict__ Xh, const short* __restrict__ Eh,
    const float* __restrict__ he2, float4* __restrict__ part)
{
    __shared__ char  lds[32768];
    __shared__ float sarr[BM * 2];
    __shared__ int   iarr[BM * 2];
    __shared__ float barr[BM * 2];

    const int t = threadIdx.x, lane = t & 63, w = t >> 6;
    const int wm = w >> 1, wn = w & 1;
    const int sid = blockIdx.x;
    const int xcd = sid & 7, j = sid >> 3;
    const int rb = xcd * 32 + (j >> 3), cb = j & 7;
    const int rowBase = rb * BM, colBase = cb * BN;

    const char* gsrc[4];
    int ldso[4];
    #pragma unroll
    for (int p = 0; p < 4; ++p) {
        int f = w * 4 + p;
        ldso[p] = f * 2048;
        const char* b = (f < 8)
            ? (const char*)Xh + (size_t)(rb * 8 + f) * 8192
            : (const char*)Eh + (size_t)(cb * 8 + (f - 8)) * 8192;
        gsrc[p] = b + lane * 16;
    }

    f32x4 acc[4][4];
    #pragma unroll
    for (int m = 0; m < 4; ++m)
        #pragma unroll
        for (int n = 0; n < 4; ++n) acc[m][n] = (f32x4){0.f, 0.f, 0.f, 0.f};

    #pragma unroll
    for (int p = 0; p < 4; ++p) {
        gload_lds16(gsrc[p],        lds + ldso[p]);
        gload_lds16(gsrc[p] + 1024, lds + ldso[p] + 1024);
    }

    #pragma unroll
    for (int c = 0; c < 4; ++c) {
        asm volatile("s_waitcnt vmcnt(0)" ::: "memory");
        __builtin_amdgcn_sched_barrier(0);
        __builtin_amdgcn_s_barrier();                  // stage c resident

        half8 A0[4], B0[4];
        #pragma unroll
        for (int m = 0; m < 4; ++m)
            A0[m] = *(const half8*)(lds + ((wm * 4 + m) * 2) * 1024 + lane * 16);
        #pragma unroll
        for (int n = 0; n < 4; ++n)
            B0[n] = *(const half8*)(lds + 16384 + ((wn * 4 + n) * 2) * 1024 + lane * 16);
        asm volatile("s_waitcnt lgkmcnt(0)" ::: "memory");
        __builtin_amdgcn_sched_barrier(0);
        __builtin_amdgcn_s_setprio(1);
        #pragma unroll
        for (int m = 0; m < 4; ++m)
            #pragma unroll
            for (int n = 0; n < 4; ++n)
                acc[m][n] = __builtin_amdgcn_mfma_f32_16x16x32_f16(A0[m], B0[n], acc[m][n], 0, 0, 0);
        __builtin_amdgcn_s_setprio(0);

        half8 A1[4], B1[4];
        #pragma unroll
        for (int m = 0; m < 4; ++m)
            A1[m] = *(const half8*)(lds + ((wm * 4 + m) * 2 + 1) * 1024 + lane * 16);
        #pragma unroll
        for (int n = 0; n < 4; ++n)
            B1[n] = *(const half8*)(lds + 16384 + ((wn * 4 + n) * 2 + 1) * 1024 + lane * 16);
        asm volatile("s_waitcnt lgkmcnt(0)" ::: "memory");
        __builtin_amdgcn_sched_barrier(0);
        __builtin_amdgcn_s_barrier();                  // all reads done

        if (c < 3) {
            #pragma unroll
            for (int p = 0; p < 4; ++p) {
                gload_lds16(gsrc[p] + (c + 1) * 2048,        lds + ldso[p]);
                gload_lds16(gsrc[p] + (c + 1) * 2048 + 1024, lds + ldso[p] + 1024);
            }
        }
        __builtin_amdgcn_sched_barrier(0);

        __builtin_amdgcn_s_setprio(1);
        #pragma unroll
        for (int m = 0; m < 4; ++m)
            #pragma unroll
            for (int n = 0; n < 4; ++n)
                acc[m][n] = __builtin_amdgcn_mfma_f32_16x16x32_f16(A1[m], B1[n], acc[m][n], 0, 0, 0);
        __builtin_amdgcn_s_setprio(0);
    }

    // epilogue: per-row best + second-best (verified rounds 9/10)
    float h2[4];
    const int c15 = lane & 15;
    #pragma unroll
    for (int n = 0; n < 4; ++n) h2[n] = he2[colBase + 64 * wn + 16 * n + c15];
    const int colg0 = colBase + 64 * wn + c15;

    #pragma unroll
    for (int m = 0; m < 4; ++m) {
        #pragma unroll
        for (int reg = 0; reg < 4; ++reg) {
            float b1 = acc[m][0][reg] - h2[0];
            int   i1 = colg0;
            float b2 = -3.4e38f;
            #pragma unroll
            for (int n = 1; n < 4; ++n) {
                float s = acc[m][n][reg] - h2[n];
                if (s > b1) { b2 = b1; b1 = s; i1 = colg0 + 16 * n; }
                else        { b2 = fmaxf(b2, s); }
            }
            #pragma unroll
            for (int msk = 1; msk <= 8; msk <<= 1) {
                float ob1 = __shfl_xor(b1, msk, 64);
                int   oi1 = __shfl_xor(i1, msk, 64);
                float ob2 = __shfl_xor(b2, msk, 64);
                if (ob1 > b1 || (ob1 == b1 && oi1 < i1)) {
                    b2 = fmaxf(b1, ob2); b1 = ob1; i1 = oi1;
                } else {
                    b2 = fmaxf(b2, ob1);
                }
            }
            if (c15 == 0) {
                int row = 64 * wm + 16 * m + 4 * (lane >> 4) + reg;
                sarr[row * 2 + wn] = b1;
                iarr[row * 2 + wn] = i1;
                barr[row * 2 + wn] = b2;
            }
        }
    }
    __syncthreads();
    if (t < BM) {
        float s0 = sarr[t*2], s1 = sarr[t*2+1];
        int   i0 = iarr[t*2], i1 = iarr[t*2+1];
        float c0 = barr[t*2], c1 = barr[t*2+1];
        float b1, b2; int bi;
        if (s1 > s0) { b1 = s1; bi = i1; b2 = fmaxf(s0, c1); }   // i0<i1: ties keep i0
        else         { b1 = s0; bi = i0; b2 = fmaxf(s1, c0); }
        part[(size_t)(rowBase + t) * GY + cb] =
            make_float4(b1, __int_as_float(bi), b2, 0.f);
    }
}

// ---- combine 8 partials, write approx result, flag near-ties -------------
__global__ __launch_bounds__(256) void vq_combine(
    const float4* __restrict__ part, const float* __restrict__ embed,
    float* __restrict__ outq, float* __restrict__ outi,
    int* __restrict__ flagCount, int* __restrict__ flagList)
{
    __shared__ int idxS[256];
    const int t = threadIdx.x;
    const int rowBase = blockIdx.x * 256;
    const int row = rowBase + t;

    float4 p = part[(size_t)row * GY];
    float b1 = p.x; int i1 = __float_as_int(p.y); float b2 = p.z;
    #pragma unroll
    for (int g = 1; g < GY; ++g) {
        float4 q = part[(size_t)row * GY + g];
        float c1 = q.x; int j1 = __float_as_int(q.y); float c2 = q.z;
        if (c1 > b1 || (c1 == b1 && j1 < i1)) { b2 = fmaxf(b1, c2); b1 = c1; i1 = j1; }
        else                                  { b2 = fmaxf(b2, c1); }
    }
    idxS[t] = i1;
    outi[row] = (float)i1;
    if (b1 - b2 < MARGIN) {
        int s = atomicAdd(flagCount, 1);
        if (s < NROWS) flagList[s] = row;
    }
    __syncthreads();

    #pragma unroll 4
    for (int q = 0; q < 64; ++q) {
        int f = t + 256 * q;
        int r = f >> 6, c4 = f & 63;
        int e = idxS[r];
        f32x4 v = *(const f32x4*)(embed + (size_t)e * DIMS + c4 * 4);
        *(f32x4*)(outq + (size_t)(rowBase + r) * DIMS + c4 * 4) = v;
    }
}

// ---- exact rescue v3: one WAVE per flagged row, 16-lane-group dots -------
// dot: lane (q = l&15) owns k-slice [q*16, q*16+16); 16 fmaf + 4-shuffle
// butterfly => all 16 lanes of the group hold the full dot (bitwise equal).
__device__ __forceinline__ float dot16(f32x4 xa, f32x4 xb, f32x4 xc, f32x4 xd,
                                       const float* __restrict__ erow, int q) {
    const f32x4* er = (const f32x4*)(erow + q * 16);
    f32x4 ea = er[0], eb = er[1], ec = er[2], ed = er[3];
    float s = xa[0] * ea[0];
    s = fmaf(xa[1], ea[1], s); s = fmaf(xa[2], ea[2], s); s = fmaf(xa[3], ea[3], s);
    s = fmaf(xb[0], eb[0], s); s = fmaf(xb[1], eb[1], s);
    s = fmaf(xb[2], eb[2], s); s = fmaf(xb[3], eb[3], s);
    s = fmaf(xc[0], ec[0], s); s = fmaf(xc[1], ec[1], s);
    s = fmaf(xc[2], ec[2], s); s = fmaf(xc[3], ec[3], s);
    s = fmaf(xd[0], ed[0], s); s = fmaf(xd[1], ed[1], s);
    s = fmaf(xd[2], ed[2], s); s = fmaf(xd[3], ed[3], s);
    s += __shfl_xor(s, 1, 64);
    s += __shfl_xor(s, 2, 64);
    s += __shfl_xor(s, 4, 64);
    s += __shfl_xor(s, 8, 64);
    return s;
}

__global__ __launch_bounds__(256) void vq_rescue(
    const float* __restrict__ x, const float* __restrict__ embed,
    const float* __restrict__ he2, const float4* __restrict__ part,
    const int* __restrict__ flagCount, const int* __restrict__ flagList,
    float* __restrict__ outq, float* __restrict__ outi)
{
    const int t = threadIdx.x, l = t & 63, w = t >> 6;
    const int q = l & 15, p = l >> 4;          // group-lane, group id
    int n = *flagCount; if (n > NROWS) n = NROWS;
    const int stride = gridDim.x * 4;

    for (int it = blockIdx.x * 4 + w; it < n; it += stride) {
        int row = flagList[it];
        const f32x4* xr = (const f32x4*)(x + (size_t)row * DIMS + q * 16);
        f32x4 xa = xr[0], xb = xr[1], xc = xr[2], xd = xr[3];

        float4 pc[GY];
        #pragma unroll
        for (int g = 0; g < GY; ++g) pc[g] = part[(size_t)row * GY + g];
        float B1 = pc[0].x;
        #pragma unroll
        for (int g = 1; g < GY; ++g) B1 = fmaxf(B1, pc[g].x);
        const float T = B1 - MARGIN;

        float wb = -3.4e38f; int wi = 0x7fffffff;
        #pragma unroll
        for (int g = 0; g < GY; ++g) {
            if (pc[g].z >= T) {
                // full 128-code scan: 4 codes/iter (group p -> code base+4i+p)
                #pragma unroll 2
                for (int i = 0; i < BN / 4; ++i) {
                    int code = g * BN + i * 4 + p;
                    float s = dot16(xa, xb, xc, xd,
                                    embed + (size_t)code * DIMS, q) - he2[code];
                    if (s > wb || (s == wb && code < wi)) { wb = s; wi = code; }
                }
            } else if (pc[g].x >= T) {
                int code = __float_as_int(pc[g].y);   // all groups: same code
                float s = dot16(xa, xb, xc, xd,
                                embed + (size_t)code * DIMS, q) - he2[code];
                if (s > wb || (s == wb && code < wi)) { wb = s; wi = code; }
            }
        }
        // merge across the 4 groups -> all 64 lanes converge
        #pragma unroll
        for (int msk = 16; msk <= 32; msk <<= 1) {
            float ob = __shfl_xor(wb, msk, 64);
            int   oi = __shfl_xor(wi, msk, 64);
            if (ob > wb || (ob == wb && oi < wi)) { wb = ob; wi = oi; }
        }
        // overwrite outputs for this row (1KB coalesced per wave)
        f32x4 v = ((const f32x4*)(embed + (size_t)wi * DIMS))[l];
        ((f32x4*)(outq + (size_t)row * DIMS))[l] = v;
        if (l == 0) outi[row] = (float)wi;
    }
}

extern "C" void kernel_launch(void* const* d_in, const int* in_sizes, int n_in,
                              void* d_out, int out_size, void* d_ws, size_t ws_size,
                              hipStream_t stream) {
    const float* x     = (const float*)d_in[0];
    const float* embed = (const float*)d_in[1];
    char* ws = (char*)d_ws;
    float*  he2      = (float*)ws;                          // 4 KB
    int*    flagCnt  = (int*)(ws + 4096);                   // 4 B
    float4* part     = (float4*)(ws + 8192);                // 4 MB
    short*  Xh       = (short*)(ws + 8192 + 4194304);       // 16.8 MB
    short*  Eh       = (short*)(ws + 8192 + 4194304 + 16777216);  // 512 KB
    int*    flagList = (int*)(ws + 8192 + 4194304 + 16777216 + 524288); // 128 KB
    float*  out  = (float*)d_out;
    float*  outi = out + (size_t)NROWS * DIMS;

    hipMemsetAsync(flagCnt, 0, 4, stream);
    xsplit<<<4096, 256, 0, stream>>>(x, Xh);
    esplit<<<KCB / 4, 256, 0, stream>>>(embed, Eh, he2);
    vq_mfma<<<(NROWS / BM) * GY, 256, 0, stream>>>(Xh, Eh, he2, part);
    vq_combine<<<NROWS / 256, 256, 0, stream>>>(part, embed, out, outi, flagCnt, flagList);
    vq_rescue<<<512, 256, 0, stream>>>(x, embed, he2, part, flagCnt, flagList, out, outi);
}